// Round 5
// baseline (1297.679 us; speedup 1.0000x reference)
//
#include <hip/hip_runtime.h>

// Problem constants (fixed by setup_inputs: B=64, C=16, T=32768, fp32)
#define B_BATCH  64
#define C_CH     16
#define T_LEN    32768
#define NROWS    (B_BATCH * C_CH)          // 1024 rows
#define SEG      4096                      // elements per block segment
#define SEGS     (T_LEN / SEG)             // 8 segments per row
#define NBLOCKS  (NROWS * SEGS)            // 8192 blocks
#define THREADS  256
#define SUB      1024                      // sub-chunk: 256 threads x float4
#define NSUB     (SEG / SUB)               // 4 sub-chunks per segment

// workspace layout: grand sum + done counter + lookback flags
struct WsLayout {
    double sum;
    unsigned int done;
    unsigned int pad;
    unsigned long long flags[NBLOCKS];     // {state:hi32, fp32 value:lo32}
};
#define FLAG_AGG 1ull
#define FLAG_INC 2ull

// DPP-based add: x + (x moved by CTRL); full-rate VALU, no LDS in chain.
template<int CTRL, int RM>
__device__ __forceinline__ float dpp_add(float x) {
    int t = __builtin_amdgcn_update_dpp(0, __builtin_bit_cast(int, x),
                                        CTRL, RM, 0xF, false);
    return x + __builtin_bit_cast(float, t);
}

// 64-lane inclusive scan via DPP (AMDGPUAtomicOptimizer sequence).
__device__ __forceinline__ float wave_incl_scan(float v) {
    v = dpp_add<0x111, 0xF>(v);   // row_shr:1
    v = dpp_add<0x112, 0xF>(v);   // row_shr:2
    v = dpp_add<0x114, 0xF>(v);   // row_shr:4
    v = dpp_add<0x118, 0xF>(v);   // row_shr:8
    v = dpp_add<0x142, 0xA>(v);   // row_bcast:15 -> rows 1,3
    v = dpp_add<0x143, 0xC>(v);   // row_bcast:31 -> rows 2,3
    return v;
}

__global__ __launch_bounds__(THREADS) void wloss_kernel(
    const float* __restrict__ pred,
    const float* __restrict__ tru,
    WsLayout* __restrict__ ws,
    float* __restrict__ out)
{
    const int bid  = blockIdx.x;
    const int row  = bid >> 3;             // /SEGS
    const int seg  = bid & (SEGS - 1);
    const int tid  = threadIdx.x;
    const int lane = tid & 63;
    const int wave = tid >> 6;

    const size_t  ebase = (size_t)row * T_LEN + (size_t)seg * SEG;
    const float4* p4 = (const float4*)(pred + ebase);
    const float4* t4 = (const float4*)(tru  + ebase);

    // ---- issue ALL segment loads up front (coalesced, 8 x 1KB/wave-instr) ----
    float4 pr[NSUB], tr[NSUB];
    #pragma unroll
    for (int c = 0; c < NSUB; ++c) {
        pr[c] = p4[c * (SUB / 4) + tid];
        tr[c] = t4[c * (SUB / 4) + tid];
    }

    // ---- segment-local block scan (4 sub-chunks, 1 barrier each) ----
    __shared__ float wtot[2][4];
    float s[NSUB][4];                      // local inclusive scans
    float excl[NSUB];                      // seg-local exclusive prefix per sub
    float lcar = 0.0f;                     // seg-local carry (block-uniform)

    #pragma unroll
    for (int c = 0; c < NSUB; ++c) {
        float4 p = pr[c], t = tr[c];
        float s1 = p.x - t.x;
        float s2 = s1 + (p.y - t.y);
        float s3 = s2 + (p.z - t.z);
        float s4 = s3 + (p.w - t.w);
        s[c][0] = s1; s[c][1] = s2; s[c][2] = s3; s[c][3] = s4;

        float v = wave_incl_scan(s4);

        const int par = c & 1;
        if (lane == 63) wtot[par][wave] = v;
        __syncthreads();

        float wpre = 0.0f, ctot = 0.0f;
        #pragma unroll
        for (int w = 0; w < 4; ++w) {
            float x = wtot[par][w];
            if (w < wave) wpre += x;
            ctot += x;
        }
        excl[c] = lcar + wpre + (v - s4);
        lcar += ctot;                      // block-uniform
    }
    // lcar == segment total (uniform across block)

    // ---- decoupled lookback for row carry-in ----
    __shared__ float carry_sh;
    if (tid == 0) {
        unsigned int vb = __builtin_bit_cast(unsigned int, lcar);
        if (seg == 0) {
            __hip_atomic_store(&ws->flags[bid], (FLAG_INC << 32) | vb,
                               __ATOMIC_RELEASE, __HIP_MEMORY_SCOPE_AGENT);
            carry_sh = 0.0f;
        } else {
            // publish aggregate first so successors can progress
            __hip_atomic_store(&ws->flags[bid], (FLAG_AGG << 32) | vb,
                               __ATOMIC_RELEASE, __HIP_MEMORY_SCOPE_AGENT);
            float carry = 0.0f;
            int j = bid - 1;               // same row, previous segments
            for (;;) {
                unsigned long long pk;
                do {
                    pk = __hip_atomic_load(&ws->flags[j], __ATOMIC_ACQUIRE,
                                           __HIP_MEMORY_SCOPE_AGENT);
                } while ((pk >> 32) == 0);
                carry += __builtin_bit_cast(float, (unsigned int)pk);
                if ((pk >> 32) == FLAG_INC) break;
                --j;
            }
            unsigned int ib = __builtin_bit_cast(unsigned int, carry + lcar);
            __hip_atomic_store(&ws->flags[bid], (FLAG_INC << 32) | ib,
                               __ATOMIC_RELEASE, __HIP_MEMORY_SCOPE_AGENT);
            carry_sh = carry;
        }
    }
    __syncthreads();
    const float carry = carry_sh;

    // ---- weighted |cumsum| accumulate ----
    double acc = 0.0;
    #pragma unroll
    for (int c = 0; c < NSUB; ++c) {
        const int   e0 = seg * SEG + c * SUB + tid * 4;
        const float w0 = (float)(T_LEN - e0);
        const float ex = carry + excl[c];
        float part = fabsf(ex + s[c][0]) * w0
                   + fabsf(ex + s[c][1]) * (w0 - 1.0f)
                   + fabsf(ex + s[c][2]) * (w0 - 2.0f)
                   + fabsf(ex + s[c][3]) * (w0 - 3.0f);
        acc += (double)part;               // fp32 partial (<~1e9) -> double
    }

    // ---- block reduction of double acc ----
    #pragma unroll
    for (int off = 32; off > 0; off >>= 1)
        acc += __shfl_down(acc, off, 64);

    __shared__ double dtot[4];
    if (lane == 0) dtot[wave] = acc;
    __syncthreads();

    if (tid == 0) {
        double sblk = dtot[0] + dtot[1] + dtot[2] + dtot[3];
        atomicAdd(&ws->sum, sblk);
        __threadfence();
        unsigned int prev = atomicAdd(&ws->done, 1u);
        if (prev == NBLOCKS - 1) {         // last block finalizes
            double total = atomicAdd(&ws->sum, 0.0);
            const double tc_     = (double)T_LEN * (double)C_CH;
            const double scaling = 2.0 / (tc_ * (tc_ + 1.0));
            out[0] = (float)(total * scaling / (double)B_BATCH);
        }
    }
}

extern "C" void kernel_launch(void* const* d_in, const int* in_sizes, int n_in,
                              void* d_out, int out_size, void* d_ws, size_t ws_size,
                              hipStream_t stream)
{
    const float* pred = (const float*)d_in[0];
    const float* tru  = (const float*)d_in[1];
    WsLayout*    ws   = (WsLayout*)d_ws;
    float*       out  = (float*)d_out;

    // zero sum + done + all lookback flags (d_ws is poisoned 0xAA pre-launch)
    hipMemsetAsync(ws, 0, sizeof(WsLayout), stream);

    wloss_kernel<<<NBLOCKS, THREADS, 0, stream>>>(pred, tru, ws, out);
}